// Round 13
// baseline (197.407 us; speedup 1.0000x reference)
//
#include <hip/hip_runtime.h>
#include <hip/hip_bf16.h>

typedef __attribute__((ext_vector_type(8))) short bf16x8;
typedef __attribute__((ext_vector_type(4))) float f32x4;
typedef __attribute__((ext_vector_type(4))) unsigned u32x4;

#define B_SZ 2
#define S_SZ 2048
#define D_SZ 1024
#define H_SZ 16
#define HD_SZ 64

static __device__ __forceinline__ short f2bf(float f) {
    unsigned u = __builtin_bit_cast(unsigned, f);
    u += 0x7FFFu + ((u >> 16) & 1u);
    return (short)(u >> 16);
}

static __device__ __forceinline__ float fexp2(float x) {
    float r; asm("v_exp_f32 %0, %1" : "=v"(r) : "v"(x)); return r;
}

static __device__ __forceinline__ unsigned cvtpk(float lo, float hi) {
    unsigned r; asm("v_cvt_pk_bf16_f32 %0, %1, %2" : "=v"(r) : "v"(lo), "v"(hi)); return r;
}

static __device__ __forceinline__ void gload16(const short* g, short* l) {
    __builtin_amdgcn_global_load_lds(
        (const __attribute__((address_space(1))) unsigned*)g,
        (__attribute__((address_space(3))) unsigned*)l,
        16, 0, 0);
}

#define SBAR() do { __builtin_amdgcn_sched_barrier(0); \
                    __builtin_amdgcn_s_barrier(); \
                    __builtin_amdgcn_sched_barrier(0); } while (0)

// ---------------- fused prep: fp32->bf16 cast + both weight transposes ----------------
__global__ __launch_bounds__(256) void k_prep(const float* __restrict__ hs, short* __restrict__ Xb,
                                              const float* __restrict__ w1, short* __restrict__ W1T,
                                              const float* __restrict__ w2, short* __restrict__ W2T) {
    __shared__ float tile[32][33];
    const int id = blockIdx.x;
    const int tid = threadIdx.x;
    if (id < 4096) {
        int i = (id * 256 + tid) * 4;
        float4 v = *reinterpret_cast<const float4*>(hs + i);
        short4 o;
        o.x = f2bf(v.x); o.y = f2bf(v.y); o.z = f2bf(v.z); o.w = f2bf(v.w);
        *reinterpret_cast<short4*>(Xb + i) = o;
        return;
    }
    const float* in;
    short* out;
    int N, bx, by;
    if (id < 7168) {
        int bid = id - 4096;
        in = w1; out = W1T; N = 3072;
        bx = bid % 96; by = bid / 96;
    } else {
        int bid = id - 7168;
        in = w2; out = W2T; N = 1024;
        bx = bid & 31; by = bid >> 5;
    }
    const int k0 = by * 32, n0 = bx * 32;
    const int tx = tid & 31, ty = tid >> 5;   // (32, 8)
    #pragma unroll
    for (int i = 0; i < 4; ++i)
        tile[ty + i * 8][tx] = in[(size_t)(k0 + ty + i * 8) * N + n0 + tx];
    __syncthreads();
    #pragma unroll
    for (int i = 0; i < 4; ++i)
        out[(size_t)(n0 + ty + i * 8) * 1024 + k0 + tx] = f2bf(tile[tx][ty + i * 8]);
}

// ---------------- QKV GEMM, 8-phase 256x256 (T3+T4+T2-full+T5) ----------------
// Q pre-scaled by 0.125*log2(e) (exp2-domain attention). V written TRANSPOSED (VT) directly.
__global__ __launch_bounds__(512, 1) void k_gemm_qkv8(
    const short* __restrict__ A, const short* __restrict__ Bt,
    const float* __restrict__ bias,
    short* __restrict__ Qo, short* __restrict__ Ko, short* __restrict__ VTo) {
    constexpr int K = 1024, NT = 16;
    __shared__ short As[2][256 * 64];
    __shared__ short Bs[2][256 * 64];
    const int tid = threadIdx.x;
    const int lane = tid & 63;
    const int w = tid >> 6;
    const int wr = w >> 2, wc = w & 3;
    const int lr = lane & 15, lc = lane >> 4;
    const int bn = blockIdx.x, bm = blockIdx.y;
    const size_t arow0 = (size_t)bm * 256;
    const size_t brow0 = (size_t)bn * 256;

    const int srl = tid >> 3;                       // 0..63 row within 64-row group
    const int sc8 = (tid & 7) ^ (srl & 7);          // swizzled source col (16B slots)
    const int dcol = (tid & 7) * 8;                 // linear LDS col (shorts)

    f32x4 acc[8][4];
    #pragma unroll
    for (int m = 0; m < 8; ++m)
        #pragma unroll
        for (int n = 0; n < 4; ++n)
            acc[m][n] = (f32x4){0.f, 0.f, 0.f, 0.f};

    auto STAGE = [&](int T, int h) {
        const int op = h >> 1, hh = h & 1;
        const int buf = T & 1;
        #pragma unroll
        for (int j = 0; j < 2; ++j) {
            int row = hh * 128 + j * 64 + srl;
            if (op == 0)
                gload16(&A[(arow0 + row) * K + T * 64 + sc8 * 8],
                        &As[buf][row * 64 + dcol]);
            else
                gload16(&Bt[(brow0 + row) * K + T * 64 + sc8 * 8],
                        &Bs[buf][row * 64 + dcol]);
        }
    };

    const int rx = (lr & 7) * 8;   // read-side swizzle XOR (shorts)
    auto LDA = [&](int buf, int rowoff, int c) {
        return *reinterpret_cast<const bf16x8*>(
            &As[buf][(wr * 128 + rowoff + lr) * 64 + (((c * 32) + lc * 8) ^ rx)]);
    };
    auto LDB = [&](int buf, int n, int c) {
        return *reinterpret_cast<const bf16x8*>(
            &Bs[buf][(wc * 64 + n * 16 + lr) * 64 + (((c * 32) + lc * 8) ^ rx)]);
    };

    bf16x8 at[4][2];
    bf16x8 bfr[4][2];

    STAGE(0, 0); STAGE(0, 1); STAGE(0, 2); STAGE(0, 3);
    STAGE(1, 2); STAGE(1, 3);
    asm volatile("s_waitcnt vmcnt(4)" ::: "memory");
    SBAR();

    for (int T = 0; T < NT; ++T) {
        const int buf = T & 1;
        // ---- phase 1
        #pragma unroll
        for (int m = 0; m < 4; ++m)
            #pragma unroll
            for (int c = 0; c < 2; ++c)
                at[m][c] = LDA(buf, m * 16, c);
        #pragma unroll
        for (int n = 0; n < 2; ++n)
            #pragma unroll
            for (int c = 0; c < 2; ++c)
                bfr[n][c] = LDB(buf, n, c);
        if (T + 1 < NT) STAGE(T + 1, 0);
        SBAR();
        __builtin_amdgcn_s_setprio(1);
        #pragma unroll
        for (int m = 0; m < 4; ++m)
            #pragma unroll
            for (int n = 0; n < 2; ++n)
                #pragma unroll
                for (int c = 0; c < 2; ++c)
                    acc[m][n] = __builtin_amdgcn_mfma_f32_16x16x32_bf16(at[m][c], bfr[n][c], acc[m][n], 0, 0, 0);
        __builtin_amdgcn_s_setprio(0);
        SBAR();
        // ---- phase 2
        #pragma unroll
        for (int n = 0; n < 2; ++n)
            #pragma unroll
            for (int c = 0; c < 2; ++c)
                bfr[2 + n][c] = LDB(buf, 2 + n, c);
        if (T + 1 < NT) STAGE(T + 1, 1);
        SBAR();
        __builtin_amdgcn_s_setprio(1);
        #pragma unroll
        for (int m = 0; m < 4; ++m)
            #pragma unroll
            for (int n = 0; n < 2; ++n)
                #pragma unroll
                for (int c = 0; c < 2; ++c)
                    acc[m][2 + n] = __builtin_amdgcn_mfma_f32_16x16x32_bf16(at[m][c], bfr[2 + n][c], acc[m][2 + n], 0, 0, 0);
        __builtin_amdgcn_s_setprio(0);
        SBAR();
        // ---- phase 3
        #pragma unroll
        for (int m = 0; m < 4; ++m)
            #pragma unroll
            for (int c = 0; c < 2; ++c)
                at[m][c] = LDA(buf, 64 + m * 16, c);
        if (T + 2 < NT) STAGE(T + 2, 2);
        SBAR();
        __builtin_amdgcn_s_setprio(1);
        #pragma unroll
        for (int m = 0; m < 4; ++m)
            #pragma unroll
            for (int n = 0; n < 2; ++n)
                #pragma unroll
                for (int c = 0; c < 2; ++c)
                    acc[4 + m][2 + n] = __builtin_amdgcn_mfma_f32_16x16x32_bf16(at[m][c], bfr[2 + n][c], acc[4 + m][2 + n], 0, 0, 0);
        __builtin_amdgcn_s_setprio(0);
        SBAR();
        // ---- phase 4
        if (T + 2 < NT) {
            STAGE(T + 2, 3);
            asm volatile("s_waitcnt vmcnt(4)" ::: "memory");
        } else {
            asm volatile("s_waitcnt vmcnt(0)" ::: "memory");
        }
        SBAR();
        __builtin_amdgcn_s_setprio(1);
        #pragma unroll
        for (int m = 0; m < 4; ++m)
            #pragma unroll
            for (int n = 0; n < 2; ++n)
                #pragma unroll
                for (int c = 0; c < 2; ++c)
                    acc[4 + m][n] = __builtin_amdgcn_mfma_f32_16x16x32_bf16(at[m][c], bfr[n][c], acc[4 + m][n], 0, 0, 0);
        __builtin_amdgcn_s_setprio(0);
        SBAR();
    }

    // epilogue: bias; Q gets exp2-domain scale; V written transposed (VT[bh][d][s])
    #pragma unroll
    for (int n = 0; n < 4; ++n) {
        const int col = bn * 256 + wc * 64 + n * 16 + lr;
        const float bv = bias[col];
        if (col < 2048) {
            const bool isq = (col < 1024);
            const float scale = isq ? 0.18033688011112042f : 1.0f;   // 0.125 * log2(e)
            short* dst = isq ? Qo : Ko;
            const int dg = col & 1023;
            const int hh = dg >> 6, dd = dg & 63;
            #pragma unroll
            for (int m = 0; m < 8; ++m) {
                #pragma unroll
                for (int r = 0; r < 4; ++r) {
                    int grow = bm * 256 + wr * 128 + m * 16 + lc * 4 + r;
                    int b = grow >> 11, s = grow & 2047;
                    dst[(((size_t)(b * H_SZ + hh)) * S_SZ + s) * HD_SZ + dd] = f2bf((acc[m][n][r] + bv) * scale);
                }
            }
        } else {
            const int dv = col - 2048;
            const int hh = dv >> 6, dt = dv & 63;
            #pragma unroll
            for (int m = 0; m < 8; ++m) {
                int grow = bm * 256 + wr * 128 + m * 16 + lc * 4;
                int b = grow >> 11, s = grow & 2047;
                short4 st;
                st.x = f2bf(acc[m][n][0] + bv);
                st.y = f2bf(acc[m][n][1] + bv);
                st.z = f2bf(acc[m][n][2] + bv);
                st.w = f2bf(acc[m][n][3] + bv);
                *reinterpret_cast<short4*>(
                    &VTo[(((size_t)(b * H_SZ + hh)) * HD_SZ + dt) * S_SZ + s]) = st;
            }
        }
    }
}

// ---------------- flash attention: LDS-FREE (K/V L2-resident, Common-mistake #7) ----------------
// 1024 blocks (4 waves), swapped QK^T, exp2 softmax, cvt_pk, T12 in-register exchange.
// No barriers at all: each wave is an independent stream; K/V frags read directly from
// global (L2-served: 512KB per bh, 4 bh/XCD fits 4MB L2). bh mapping keeps XCD locality.
__global__ __launch_bounds__(256) void k_attn(const short* __restrict__ Q,
                                              const short* __restrict__ Kv,
                                              const short* __restrict__ VT,
                                              short* __restrict__ O) {
    const int id = blockIdx.x;
    const int bh = ((id & 7) << 2) | ((id >> 3) & 3);
    const int h = bh & 15;
    const int bb = bh >> 4;
    const int g = id >> 5, oct = g >> 3, gr = g & 7;
    const int qt = (oct == 0) ? 31 - gr : (oct == 1) ? 16 + gr : (oct == 2) ? 15 - gr : gr;
    const int tid = threadIdx.x;
    const int lane = tid & 63, w = tid >> 6;        // w 0..3
    const int lr = lane & 15, lc = lane >> 4;
    const int qrow0 = qt * 64 + w * 16;
    const size_t base = (size_t)bh * S_SZ * HD_SZ;

    bf16x8 qf[2];
    #pragma unroll
    for (int c = 0; c < 2; ++c)
        qf[c] = *reinterpret_cast<const bf16x8*>(&Q[base + (size_t)(qrow0 + lr) * HD_SZ + c * 32 + lc * 8]);

    float l_run = 0.f;                      // per-lane partial row sum (reduced at epilogue)
    f32x4 o_acc[4];                         // O[q=lc*4+r][d=n*16+lr]
    #pragma unroll
    for (int n = 0; n < 4; ++n) o_acc[n] = (f32x4){0.f, 0.f, 0.f, 0.f};

    // direct-from-global fragment pointers (incremental):
    // K[bh][s][64]: s = kt*64 + n*16 + lr, col c*32+lc*8  -> kt:+4096, n:+1024, c:+32 shorts
    // VT[bh][d][S]: d = n*16 + lr, s = kt*64 + c*32+lc*8  -> kt:+64, n:+32768, c:+32 shorts
    const short* kp = &Kv[base + (size_t)lr * HD_SZ + lc * 8];
    const short* vp = &VT[base + (size_t)lr * S_SZ + lc * 8];

    const int q_row = qrow0 + lr;
    const bool b0 = (lane & 16) != 0;   // lc bit0
    const bool b1 = (lane & 32) != 0;   // lc bit1

    for (int kt = 0; kt <= qt; ++kt) {
        // K fragments (8 x 16B, L2-served)
        bf16x8 kf[4][2];
        #pragma unroll
        for (int n = 0; n < 4; ++n)
            #pragma unroll
            for (int c = 0; c < 2; ++c)
                kf[n][c] = *reinterpret_cast<const bf16x8*>(kp + n * 1024 + c * 32);
        // S2^T = K Q^T (log2 domain): lane holds S2[q=q_row][k = kt*64 + 16n + 4lc + r]
        f32x4 sf[4];
        #pragma unroll
        for (int n = 0; n < 4; ++n) {
            f32x4 z = (f32x4){0.f, 0.f, 0.f, 0.f};
            #pragma unroll
            for (int c = 0; c < 2; ++c)
                z = __builtin_amdgcn_mfma_f32_16x16x32_bf16(kf[n][c], qf[c], z, 0, 0, 0);
            sf[n] = z;
        }
        // V fragments issued now — latency hides under softmax VALU
        bf16x8 vf[4][2];
        #pragma unroll
        for (int n = 0; n < 4; ++n)
            #pragma unroll
            for (int c = 0; c < 2; ++c)
                vf[n][c] = *reinterpret_cast<const bf16x8*>(vp + n * 32768 + c * 32);
        kp += 4096; vp += 64;
        if (kt == qt) {
            const int kb = kt * 64 + lc * 4 - q_row;
            #pragma unroll
            for (int n = 0; n < 4; ++n)
                #pragma unroll
                for (int r = 0; r < 4; ++r)
                    sf[n][r] = (kb + n * 16 + r > 0) ? -14427.0f : sf[n][r];
        }
        // P = exp2(S2); per-lane partial row sum
        float rs = 0.f;
        #pragma unroll
        for (int n = 0; n < 4; ++n)
            #pragma unroll
            for (int r = 0; r < 4; ++r) {
                float pv = fexp2(sf[n][r]);
                sf[n][r] = pv;
                rs += pv;
            }
        l_run += rs;
        // pack to bf16 pairs (v_cvt_pk_bf16_f32)
        unsigned Apk0 = cvtpk(sf[0][0], sf[0][1]), Apk1 = cvtpk(sf[0][2], sf[0][3]);
        unsigned Bpk0 = cvtpk(sf[1][0], sf[1][1]), Bpk1 = cvtpk(sf[1][2], sf[1][3]);
        unsigned Cpk0 = cvtpk(sf[2][0], sf[2][1]), Cpk1 = cvtpk(sf[2][2], sf[2][3]);
        unsigned Dpk0 = cvtpk(sf[3][0], sf[3][1]), Dpk1 = cvtpk(sf[3][2], sf[3][3]);
        // ---- T12: in-register P -> A-frag exchange (no LDS) ----
        unsigned x0 = __shfl_xor(b0 ? Apk0 : Bpk0, 16);
        unsigned x1 = __shfl_xor(b0 ? Apk1 : Bpk1, 16);
        unsigned x2 = __shfl_xor(b0 ? Cpk0 : Dpk0, 16);
        unsigned x3 = __shfl_xor(b0 ? Cpk1 : Dpk1, 16);
        unsigned y0 = __shfl_xor(b1 ? Apk0 : Bpk0, 32);
        unsigned y1 = __shfl_xor(b1 ? Apk1 : Bpk1, 32);
        unsigned y2 = __shfl_xor(b1 ? Cpk0 : Dpk0, 32);
        unsigned y3 = __shfl_xor(b1 ? Cpk1 : Dpk1, 32);
        unsigned z0 = __shfl_xor(b1 ? Apk0 : Bpk0, 48);
        unsigned z1 = __shfl_xor(b1 ? Apk1 : Bpk1, 48);
        unsigned z2 = __shfl_xor(b1 ? Cpk0 : Dpk0, 48);
        unsigned z3 = __shfl_xor(b1 ? Cpk1 : Dpk1, 48);
        u32x4 pv0 = { b1 ? (b0 ? x0 : y0) : (b0 ? z0 : Apk0),
                      b1 ? (b0 ? x1 : y1) : (b0 ? z1 : Apk1),
                      b1 ? (b0 ? Bpk0 : z0) : (b0 ? y0 : x0),
                      b1 ? (b0 ? Bpk1 : z1) : (b0 ? y1 : x1) };
        u32x4 pv1 = { b1 ? (b0 ? x2 : y2) : (b0 ? z2 : Cpk0),
                      b1 ? (b0 ? x3 : y3) : (b0 ? z3 : Cpk1),
                      b1 ? (b0 ? Dpk0 : z2) : (b0 ? y2 : x2),
                      b1 ? (b0 ? Dpk1 : z3) : (b0 ? y3 : x3) };
        bf16x8 paA = __builtin_bit_cast(bf16x8, pv0);
        bf16x8 paB = __builtin_bit_cast(bf16x8, pv1);
        // PV (vf long since issued -> landed)
        #pragma unroll
        for (int c = 0; c < 2; ++c) {
            bf16x8 pa = c ? paB : paA;
            #pragma unroll
            for (int n = 0; n < 4; ++n)
                o_acc[n] = __builtin_amdgcn_mfma_f32_16x16x32_bf16(pa, vf[n][c], o_acc[n], 0, 0, 0);
        }
    }

    // epilogue: reduce partial l across lc, then normalize
    l_run += __shfl_xor(l_run, 16);
    l_run += __shfl_xor(l_run, 32);
    float li[4];
    #pragma unroll
    for (int r = 0; r < 4; ++r)
        li[r] = 1.0f / __shfl(l_run, lc * 4 + r);
    #pragma unroll
    for (int n = 0; n < 4; ++n) {
        #pragma unroll
        for (int r = 0; r < 4; ++r) {
            float v = o_acc[n][r] * li[r];
            int s = qrow0 + lc * 4 + r;
            O[((size_t)bb * S_SZ + s) * D_SZ + h * 64 + n * 16 + lr] = f2bf(v);
        }
    }
}

// ---------------- proj GEMM (m97 structure) ----------------
__global__ __launch_bounds__(256) void k_gemm_proj(
    const short* __restrict__ A, const short* __restrict__ Bt,
    const float* __restrict__ bias, float* __restrict__ out) {
    constexpr int K = 1024;
    constexpr int N = 1024;
    __shared__ short As[128 * 64];
    __shared__ short Bs[128 * 64];
    const int tid = threadIdx.x;
    const int lane = tid & 63;
    const int w = tid >> 6;
    const int wm = w >> 1, wn = w & 1;
    const int lr = lane & 15, lc = lane >> 4;
    const int bn = blockIdx.x, bm = blockIdx.y;
    const size_t arow0 = (size_t)bm * 128;
    const size_t brow0 = (size_t)bn * 128;

    const short* aptr[4];
    const short* bptr[4];
    short* alds[4];
    short* blds[4];
    #pragma unroll
    for (int i = 0; i < 4; ++i) {
        int cid = w * 4 + i;
        int row = cid * 8 + (lane >> 3);
        int col = (lane & 7) * 8;
        aptr[i] = A + (arow0 + row) * K + col;
        bptr[i] = Bt + (brow0 + row) * K + col;
        alds[i] = &As[cid * 512];
        blds[i] = &Bs[cid * 512];
    }

    f32x4 acc[4][4];
    #pragma unroll
    for (int m = 0; m < 4; ++m)
        #pragma unroll
        for (int n = 0; n < 4; ++n)
            acc[m][n] = (f32x4){0.f, 0.f, 0.f, 0.f};

    for (int kt = 0; kt < K; kt += 64) {
        __syncthreads();
        #pragma unroll
        for (int i = 0; i < 4; ++i) {
            gload16(aptr[i] + kt, alds[i]);
            gload16(bptr[i] + kt, blds[i]);
        }
        __syncthreads();
        #pragma unroll
        for (int c = 0; c < 2; ++c) {
            bf16x8 af[4], bfr[4];
            #pragma unroll
            for (int m = 0; m < 4; ++m)
                af[m] = *reinterpret_cast<const bf16x8*>(&As[(wm * 64 + m * 16 + lr) * 64 + c * 32 + lc * 8]);
            #pragma unroll
            for (int n = 0; n < 4; ++n)
                bfr[n] = *reinterpret_cast<const bf16x8*>(&Bs[(wn * 64 + n * 16 + lr) * 64 + c * 32 + lc * 8]);
            #pragma unroll
            for (int m = 0; m < 4; ++m)
                #pragma unroll
                for (int n = 0; n < 4; ++n)
                    acc[m][n] = __builtin_amdgcn_mfma_f32_16x16x32_bf16(af[m], bfr[n], acc[m][n], 0, 0, 0);
        }
    }

    #pragma unroll
    for (int n = 0; n < 4; ++n) {
        const int col = bn * 128 + wn * 64 + n * 16 + lr;
        const float bv = bias[col];
        #pragma unroll
        for (int m = 0; m < 4; ++m) {
            #pragma unroll
            for (int r = 0; r < 4; ++r) {
                int grow = bm * 128 + wm * 64 + m * 16 + lc * 4 + r;
                out[(size_t)grow * N + col] = acc[m][n][r] + bv;
            }
        }
    }
}

extern "C" void kernel_launch(void* const* d_in, const int* in_sizes, int n_in,
                              void* d_out, int out_size, void* d_ws, size_t ws_size,
                              hipStream_t stream) {
    (void)in_sizes; (void)n_in; (void)out_size; (void)ws_size;
    const float* hs     = (const float*)d_in[0];
    const float* w_attn = (const float*)d_in[1];
    const float* b_attn = (const float*)d_in[2];
    const float* w_proj = (const float*)d_in[3];
    const float* b_proj = (const float*)d_in[4];
    float* out = (float*)d_out;
    char* ws = (char*)d_ws;

    short* Xb  = (short*)(ws + 0);         // 8 MiB  [4096][1024] bf16 (dead after qkv8)
    short* W1T = (short*)(ws + 8388608);   // 6 MiB  [3072][1024] bf16 (dead after qkv8)
    short* W2T = (short*)(ws + 14680064);  // 2 MiB  [1024][1024] bf16
    short* Qb  = (short*)(ws + 16777216);  // 8 MiB  [B][H][S][64] (pre-scaled 0.125*log2e)
    short* Kb  = (short*)(ws + 25165824);  // 8 MiB  [B][H][S][64]
    short* VTb = (short*)(ws + 33554432);  // 8 MiB  [B][H][64][S] (written by qkv8 directly)
    short* Ob  = (short*)(ws + 0);         // 8 MiB  [B][S][1024]  (over Xb, dead by attn)

    k_prep<<<dim3(8192), dim3(256), 0, stream>>>(hs, Xb, w_attn, W1T, w_proj, W2T);
    k_gemm_qkv8<<<dim3(12, 16), dim3(512), 0, stream>>>(Xb, W1T, b_attn, Qb, Kb, VTb);
    k_attn<<<dim3(1024), dim3(256), 0, stream>>>(Qb, Kb, VTb, Ob);
    k_gemm_proj<<<dim3(8, 32), dim3(256), 0, stream>>>(Ob, W2T, b_proj, out);
}

// Round 14
// 110.356 us; speedup vs baseline: 1.7888x; 1.7888x over previous
//
#include <hip/hip_runtime.h>
#include <hip/hip_bf16.h>

typedef __attribute__((ext_vector_type(8))) short bf16x8;
typedef __attribute__((ext_vector_type(4))) float f32x4;
typedef __attribute__((ext_vector_type(4))) unsigned u32x4;

#define B_SZ 2
#define S_SZ 2048
#define D_SZ 1024
#define H_SZ 16
#define HD_SZ 64

static __device__ __forceinline__ short f2bf(float f) {
    unsigned u = __builtin_bit_cast(unsigned, f);
    u += 0x7FFFu + ((u >> 16) & 1u);
    return (short)(u >> 16);
}

static __device__ __forceinline__ float fexp2(float x) {
    float r; asm("v_exp_f32 %0, %1" : "=v"(r) : "v"(x)); return r;
}

static __device__ __forceinline__ unsigned cvtpk(float lo, float hi) {
    unsigned r; asm("v_cvt_pk_bf16_f32 %0, %1, %2" : "=v"(r) : "v"(lo), "v"(hi)); return r;
}

static __device__ __forceinline__ void gload16(const short* g, short* l) {
    __builtin_amdgcn_global_load_lds(
        (const __attribute__((address_space(1))) unsigned*)g,
        (__attribute__((address_space(3))) unsigned*)l,
        16, 0, 0);
}

#define SBAR() do { __builtin_amdgcn_sched_barrier(0); \
                    __builtin_amdgcn_s_barrier(); \
                    __builtin_amdgcn_sched_barrier(0); } while (0)

// ---------------- fused prep: fp32->bf16 cast + both weight transposes ----------------
__global__ __launch_bounds__(256) void k_prep(const float* __restrict__ hs, short* __restrict__ Xb,
                                              const float* __restrict__ w1, short* __restrict__ W1T,
                                              const float* __restrict__ w2, short* __restrict__ W2T) {
    __shared__ float tile[32][33];
    const int id = blockIdx.x;
    const int tid = threadIdx.x;
    if (id < 4096) {
        int i = (id * 256 + tid) * 4;
        float4 v = *reinterpret_cast<const float4*>(hs + i);
        short4 o;
        o.x = f2bf(v.x); o.y = f2bf(v.y); o.z = f2bf(v.z); o.w = f2bf(v.w);
        *reinterpret_cast<short4*>(Xb + i) = o;
        return;
    }
    const float* in;
    short* out;
    int N, bx, by;
    if (id < 7168) {
        int bid = id - 4096;
        in = w1; out = W1T; N = 3072;
        bx = bid % 96; by = bid / 96;
    } else {
        int bid = id - 7168;
        in = w2; out = W2T; N = 1024;
        bx = bid & 31; by = bid >> 5;
    }
    const int k0 = by * 32, n0 = bx * 32;
    const int tx = tid & 31, ty = tid >> 5;   // (32, 8)
    #pragma unroll
    for (int i = 0; i < 4; ++i)
        tile[ty + i * 8][tx] = in[(size_t)(k0 + ty + i * 8) * N + n0 + tx];
    __syncthreads();
    #pragma unroll
    for (int i = 0; i < 4; ++i)
        out[(size_t)(n0 + ty + i * 8) * 1024 + k0 + tx] = f2bf(tile[tx][ty + i * 8]);
}

// ---------------- QKV GEMM, 2-phase 256x192 (T3+T4+T2+T5), 256 blocks = full chip ----------------
// Q pre-scaled by 0.125*log2(e) (exp2-domain attention). V written TRANSPOSED (VT) directly.
// XCD-local block remap: each XCD gets a 4bm x 8bn region (per-XCD fetch ~5MB, L2-fits).
__global__ __launch_bounds__(512, 1) void k_gemm_qkv8(
    const short* __restrict__ A, const short* __restrict__ Bt,
    const float* __restrict__ bias,
    short* __restrict__ Qo, short* __restrict__ Ko, short* __restrict__ VTo) {
    constexpr int K = 1024, NT = 16;
    __shared__ short As[2][256 * 64];   // 64 KB
    __shared__ short Bs[2][192 * 64];   // 48 KB
    const int tid = threadIdx.x;
    const int lane = tid & 63;
    const int w = tid >> 6;
    const int wr = w >> 2, wc = w & 3;
    const int lr = lane & 15, lc = lane >> 4;
    const int bid = blockIdx.x;
    const int xcd = bid & 7, local = bid >> 3;            // dispatch round-robins XCDs
    const int bm = (xcd >> 1) * 4 + (local >> 3);         // 16 bm values
    const int bn = (xcd & 1) * 8 + (local & 7);           // 16 bn values
    const size_t arow0 = (size_t)bm * 256;
    const size_t brow0 = (size_t)bn * 192;

    const int srl = tid >> 3;                       // 0..63 row within 64-row group
    const int sc8 = (tid & 7) ^ (srl & 7);          // swizzled source col (16B slots)
    const int dcol = (tid & 7) * 8;                 // linear LDS col (shorts)

    f32x4 acc[8][3];
    #pragma unroll
    for (int m = 0; m < 8; ++m)
        #pragma unroll
        for (int n = 0; n < 3; ++n)
            acc[m][n] = (f32x4){0.f, 0.f, 0.f, 0.f};

    auto STAGE_A = [&](int T) {
        const int buf = T & 1;
        #pragma unroll
        for (int j = 0; j < 4; ++j) {
            int row = j * 64 + srl;
            gload16(&A[(arow0 + row) * K + T * 64 + sc8 * 8], &As[buf][row * 64 + dcol]);
        }
    };
    auto STAGE_B = [&](int T) {
        const int buf = T & 1;
        #pragma unroll
        for (int j = 0; j < 3; ++j) {
            int row = j * 64 + srl;
            gload16(&Bt[(brow0 + row) * K + T * 64 + sc8 * 8], &Bs[buf][row * 64 + dcol]);
        }
    };

    const int rx = (lr & 7) * 8;   // read-side swizzle XOR (shorts)
    auto LDA = [&](int buf, int rowoff, int c) {
        return *reinterpret_cast<const bf16x8*>(
            &As[buf][(wr * 128 + rowoff + lr) * 64 + (((c * 32) + lc * 8) ^ rx)]);
    };
    auto LDB = [&](int buf, int n, int c) {
        return *reinterpret_cast<const bf16x8*>(
            &Bs[buf][(wc * 48 + n * 16 + lr) * 64 + (((c * 32) + lc * 8) ^ rx)]);
    };

    bf16x8 at[4][2];    // transient A frags (current m-half)
    bf16x8 bfr[3][2];   // B frags (all 3 n, read once per tile in p1)

    // prologue: A(0) + B(0) + B(1); A(0)/B(0) must land, B(1) may stay in flight
    STAGE_A(0); STAGE_B(0); STAGE_B(1);
    asm volatile("s_waitcnt vmcnt(3)" ::: "memory");
    SBAR();

    for (int T = 0; T < NT; ++T) {
        const int buf = T & 1;
        // ---- phase 1: read A-mh0 + B all; stage A(T+1); MFMA mh0 x n (24)
        #pragma unroll
        for (int m = 0; m < 4; ++m)
            #pragma unroll
            for (int c = 0; c < 2; ++c)
                at[m][c] = LDA(buf, m * 16, c);
        #pragma unroll
        for (int n = 0; n < 3; ++n)
            #pragma unroll
            for (int c = 0; c < 2; ++c)
                bfr[n][c] = LDB(buf, n, c);
        if (T + 1 < NT) STAGE_A(T + 1);
        SBAR();
        __builtin_amdgcn_s_setprio(1);
        #pragma unroll
        for (int m = 0; m < 4; ++m)
            #pragma unroll
            for (int n = 0; n < 3; ++n)
                #pragma unroll
                for (int c = 0; c < 2; ++c)
                    acc[m][n] = __builtin_amdgcn_mfma_f32_16x16x32_bf16(at[m][c], bfr[n][c], acc[m][n], 0, 0, 0);
        __builtin_amdgcn_s_setprio(0);
        SBAR();
        // ---- phase 2: read A-mh1; stage B(T+2); counted vmcnt(3); MFMA mh1 x n (24)
        #pragma unroll
        for (int m = 0; m < 4; ++m)
            #pragma unroll
            for (int c = 0; c < 2; ++c)
                at[m][c] = LDA(buf, 64 + m * 16, c);
        if (T + 2 < NT) {
            STAGE_B(T + 2);
            asm volatile("s_waitcnt vmcnt(3)" ::: "memory");
        } else {
            asm volatile("s_waitcnt vmcnt(0)" ::: "memory");
        }
        SBAR();
        __builtin_amdgcn_s_setprio(1);
        #pragma unroll
        for (int m = 0; m < 4; ++m)
            #pragma unroll
            for (int n = 0; n < 3; ++n)
                #pragma unroll
                for (int c = 0; c < 2; ++c)
                    acc[4 + m][n] = __builtin_amdgcn_mfma_f32_16x16x32_bf16(at[m][c], bfr[n][c], acc[4 + m][n], 0, 0, 0);
        __builtin_amdgcn_s_setprio(0);
        SBAR();
    }

    // epilogue: bias; Q gets exp2-domain scale; V written transposed (VT[bh][d][s])
    #pragma unroll
    for (int n = 0; n < 3; ++n) {
        const int col = bn * 192 + wc * 48 + n * 16 + lr;
        const float bv = bias[col];
        if (col < 2048) {
            const bool isq = (col < 1024);
            const float scale = isq ? 0.18033688011112042f : 1.0f;   // 0.125 * log2(e)
            short* dst = isq ? Qo : Ko;
            const int dg = col & 1023;
            const int hh = dg >> 6, dd = dg & 63;
            #pragma unroll
            for (int m = 0; m < 8; ++m) {
                #pragma unroll
                for (int r = 0; r < 4; ++r) {
                    int grow = bm * 256 + wr * 128 + m * 16 + lc * 4 + r;
                    int b = grow >> 11, s = grow & 2047;
                    dst[(((size_t)(b * H_SZ + hh)) * S_SZ + s) * HD_SZ + dd] = f2bf((acc[m][n][r] + bv) * scale);
                }
            }
        } else {
            const int dv = col - 2048;
            const int hh = dv >> 6, dt = dv & 63;
            #pragma unroll
            for (int m = 0; m < 8; ++m) {
                int grow = bm * 256 + wr * 128 + m * 16 + lc * 4;
                int b = grow >> 11, s = grow & 2047;
                short4 st;
                st.x = f2bf(acc[m][n][0] + bv);
                st.y = f2bf(acc[m][n][1] + bv);
                st.z = f2bf(acc[m][n][2] + bv);
                st.w = f2bf(acc[m][n][3] + bv);
                *reinterpret_cast<short4*>(
                    &VTo[(((size_t)(b * H_SZ + hh)) * HD_SZ + dt) * S_SZ + s]) = st;
            }
        }
    }
}

// ---------------- flash attention (R12 known-good, 49us): 1024 single-qtile blocks,
// swapped QK^T, exp2 softmax, cvt_pk, T12 exchange, LDS dbuf staging, balanced qt ----------------
__global__ __launch_bounds__(256) void k_attn(const short* __restrict__ Q,
                                              const short* __restrict__ Kv,
                                              const short* __restrict__ VT,
                                              short* __restrict__ O) {
    __shared__ short Ks[2][64 * 64];
    __shared__ short Vs[2][64 * 64];
    const int id = blockIdx.x;
    const int bh = ((id & 7) << 2) | ((id >> 3) & 3);
    const int h = bh & 15;
    const int bb = bh >> 4;
    const int g = id >> 5, oct = g >> 3, gr = g & 7;
    const int qt = (oct == 0) ? 31 - gr : (oct == 1) ? 16 + gr : (oct == 2) ? 15 - gr : gr;
    const int tid = threadIdx.x;
    const int lane = tid & 63, w = tid >> 6;        // w 0..3
    const int lr = lane & 15, lc = lane >> 4;
    const int qrow0 = qt * 64 + w * 16;
    const size_t base = (size_t)bh * S_SZ * HD_SZ;

    bf16x8 qf[2];
    #pragma unroll
    for (int c = 0; c < 2; ++c)
        qf[c] = *reinterpret_cast<const bf16x8*>(&Q[base + (size_t)(qrow0 + lr) * HD_SZ + c * 32 + lc * 8]);

    float l_run = 0.f;                      // per-lane partial row sum (reduced at epilogue)
    f32x4 o_acc[4];                         // O[q=lc*4+r][d=n*16+lr]
    #pragma unroll
    for (int n = 0; n < 4; ++n) o_acc[n] = (f32x4){0.f, 0.f, 0.f, 0.f};

    // async staging, incremental pointers: K tile advances 4096 shorts/kt, VT 64/kt
    const int srow = tid >> 3;                      // 0..31
    const int sslot = (tid & 7) ^ (srow & 7);       // source 16B-slot pre-swizzled by row&7
    const short* kp = &Kv[base + (size_t)srow * HD_SZ + sslot * 8];
    const short* vp = &VT[base + (size_t)srow * S_SZ + sslot * 8];
    auto STAGE = [&](int b) {
        gload16(kp, &Ks[b][tid * 8]);
        gload16(kp + 2048, &Ks[b][2048 + tid * 8]);
        gload16(vp, &Vs[b][tid * 8]);
        gload16(vp + 32 * S_SZ, &Vs[b][2048 + tid * 8]);
        kp += 4096; vp += 64;
    };

    const int q_row = qrow0 + lr;
    const int rxa = (lr & 7) * 8;       // read-side swizzle XOR (shorts)
    const bool b0 = (lane & 16) != 0;   // lc bit0
    const bool b1 = (lane & 32) != 0;   // lc bit1

    STAGE(0);
    asm volatile("s_waitcnt vmcnt(0)" ::: "memory");
    SBAR();

    for (int kt = 0; kt <= qt; ++kt) {
        const int buf = kt & 1;
        if (kt < qt) STAGE(buf ^ 1);
        {
            // S2^T = K Q^T (log2 domain): lane holds S2[q=q_row][k = kt*64 + 16n + 4lc + r]
            f32x4 sf[4];
            #pragma unroll
            for (int n = 0; n < 4; ++n) {
                f32x4 z = (f32x4){0.f, 0.f, 0.f, 0.f};
                #pragma unroll
                for (int c = 0; c < 2; ++c) {
                    bf16x8 kf = *reinterpret_cast<const bf16x8*>(
                        &Ks[buf][(n * 16 + lr) * 64 + ((c * 32 + lc * 8) ^ rxa)]);
                    z = __builtin_amdgcn_mfma_f32_16x16x32_bf16(kf, qf[c], z, 0, 0, 0);
                }
                sf[n] = z;
            }
            if (kt == qt) {
                const int kb = kt * 64 + lc * 4 - q_row;
                #pragma unroll
                for (int n = 0; n < 4; ++n)
                    #pragma unroll
                    for (int r = 0; r < 4; ++r)
                        sf[n][r] = (kb + n * 16 + r > 0) ? -14427.0f : sf[n][r];
            }
            // P = exp2(S2); per-lane partial row sum
            float rs = 0.f;
            #pragma unroll
            for (int n = 0; n < 4; ++n)
                #pragma unroll
                for (int r = 0; r < 4; ++r) {
                    float pv = fexp2(sf[n][r]);
                    sf[n][r] = pv;
                    rs += pv;
                }
            l_run += rs;
            // pack to bf16 pairs (v_cvt_pk_bf16_f32)
            unsigned Apk0 = cvtpk(sf[0][0], sf[0][1]), Apk1 = cvtpk(sf[0][2], sf[0][3]);
            unsigned Bpk0 = cvtpk(sf[1][0], sf[1][1]), Bpk1 = cvtpk(sf[1][2], sf[1][3]);
            unsigned Cpk0 = cvtpk(sf[2][0], sf[2][1]), Cpk1 = cvtpk(sf[2][2], sf[2][3]);
            unsigned Dpk0 = cvtpk(sf[3][0], sf[3][1]), Dpk1 = cvtpk(sf[3][2], sf[3][3]);
            // ---- T12: in-register P -> A-frag exchange (no LDS) ----
            unsigned x0 = __shfl_xor(b0 ? Apk0 : Bpk0, 16);
            unsigned x1 = __shfl_xor(b0 ? Apk1 : Bpk1, 16);
            unsigned x2 = __shfl_xor(b0 ? Cpk0 : Dpk0, 16);
            unsigned x3 = __shfl_xor(b0 ? Cpk1 : Dpk1, 16);
            unsigned y0 = __shfl_xor(b1 ? Apk0 : Bpk0, 32);
            unsigned y1 = __shfl_xor(b1 ? Apk1 : Bpk1, 32);
            unsigned y2 = __shfl_xor(b1 ? Cpk0 : Dpk0, 32);
            unsigned y3 = __shfl_xor(b1 ? Cpk1 : Dpk1, 32);
            unsigned z0 = __shfl_xor(b1 ? Apk0 : Bpk0, 48);
            unsigned z1 = __shfl_xor(b1 ? Apk1 : Bpk1, 48);
            unsigned z2 = __shfl_xor(b1 ? Cpk0 : Dpk0, 48);
            unsigned z3 = __shfl_xor(b1 ? Cpk1 : Dpk1, 48);
            u32x4 pv0 = { b1 ? (b0 ? x0 : y0) : (b0 ? z0 : Apk0),
                          b1 ? (b0 ? x1 : y1) : (b0 ? z1 : Apk1),
                          b1 ? (b0 ? Bpk0 : z0) : (b0 ? y0 : x0),
                          b1 ? (b0 ? Bpk1 : z1) : (b0 ? y1 : x1) };
            u32x4 pv1 = { b1 ? (b0 ? x2 : y2) : (b0 ? z2 : Cpk0),
                          b1 ? (b0 ? x3 : y3) : (b0 ? z3 : Cpk1),
                          b1 ? (b0 ? Dpk0 : z2) : (b0 ? y2 : x2),
                          b1 ? (b0 ? Dpk1 : z3) : (b0 ? y3 : x3) };
            bf16x8 paA = __builtin_bit_cast(bf16x8, pv0);
            bf16x8 paB = __builtin_bit_cast(bf16x8, pv1);
            // PV
            #pragma unroll
            for (int c = 0; c < 2; ++c) {
                bf16x8 pa = c ? paB : paA;
                #pragma unroll
                for (int n = 0; n < 4; ++n) {
                    bf16x8 vf = *reinterpret_cast<const bf16x8*>(
                        &Vs[buf][(n * 16 + lr) * 64 + ((c * 32 + lc * 8) ^ rxa)]);
                    o_acc[n] = __builtin_amdgcn_mfma_f32_16x16x32_bf16(pa, vf, o_acc[n], 0, 0, 0);
                }
            }
        }
        asm volatile("s_waitcnt vmcnt(0)" ::: "memory");
        SBAR();
    }

    // epilogue: reduce partial l across lc, then normalize
    l_run += __shfl_xor(l_run, 16);
    l_run += __shfl_xor(l_run, 32);
    float li[4];
    #pragma unroll
    for (int r = 0; r < 4; ++r)
        li[r] = 1.0f / __shfl(l_run, lc * 4 + r);
    #pragma unroll
    for (int n = 0; n < 4; ++n) {
        #pragma unroll
        for (int r = 0; r < 4; ++r) {
            float v = o_acc[n][r] * li[r];
            int s = qrow0 + lc * 4 + r;
            O[((size_t)bb * S_SZ + s) * D_SZ + h * 64 + n * 16 + lr] = f2bf(v);
        }
    }
}

// ---------------- proj GEMM (m97 structure) ----------------
__global__ __launch_bounds__(256) void k_gemm_proj(
    const short* __restrict__ A, const short* __restrict__ Bt,
    const float* __restrict__ bias, float* __restrict__ out) {
    constexpr int K = 1024;
    constexpr int N = 1024;
    __shared__ short As[128 * 64];
    __shared__ short Bs[128 * 64];
    const int tid = threadIdx.x;
    const int lane = tid & 63;
    const int w = tid >> 6;
    const int wm = w >> 1, wn = w & 1;
    const int lr = lane & 15, lc = lane >> 4;
    const int bn = blockIdx.x, bm = blockIdx.y;
    const size_t arow0 = (size_t)bm * 128;
    const size_t brow0 = (size_t)bn * 128;

    const short* aptr[4];
    const short* bptr[4];
    short* alds[4];
    short* blds[4];
    #pragma unroll
    for (int i = 0; i < 4; ++i) {
        int cid = w * 4 + i;
        int row = cid * 8 + (lane >> 3);
        int col = (lane & 7) * 8;
        aptr[i] = A + (arow0 + row) * K + col;
        bptr[i] = Bt + (brow0 + row) * K + col;
        alds[i] = &As[cid * 512];
        blds[i] = &Bs[cid * 512];
    }

    f32x4 acc[4][4];
    #pragma unroll
    for (int m = 0; m < 4; ++m)
        #pragma unroll
        for (int n = 0; n < 4; ++n)
            acc[m][n] = (f32x4){0.f, 0.f, 0.f, 0.f};

    for (int kt = 0; kt < K; kt += 64) {
        __syncthreads();
        #pragma unroll
        for (int i = 0; i < 4; ++i) {
            gload16(aptr[i] + kt, alds[i]);
            gload16(bptr[i] + kt, blds[i]);
        }
        __syncthreads();
        #pragma unroll
        for (int c = 0; c < 2; ++c) {
            bf16x8 af[4], bfr[4];
            #pragma unroll
            for (int m = 0; m < 4; ++m)
                af[m] = *reinterpret_cast<const bf16x8*>(&As[(wm * 64 + m * 16 + lr) * 64 + c * 32 + lc * 8]);
            #pragma unroll
            for (int n = 0; n < 4; ++n)
                bfr[n] = *reinterpret_cast<const bf16x8*>(&Bs[(wn * 64 + n * 16 + lr) * 64 + c * 32 + lc * 8]);
            #pragma unroll
            for (int m = 0; m < 4; ++m)
                #pragma unroll
                for (int n = 0; n < 4; ++n)
                    acc[m][n] = __builtin_amdgcn_mfma_f32_16x16x32_bf16(af[m], bfr[n], acc[m][n], 0, 0, 0);
        }
    }

    #pragma unroll
    for (int n = 0; n < 4; ++n) {
        const int col = bn * 128 + wn * 64 + n * 16 + lr;
        const float bv = bias[col];
        #pragma unroll
        for (int m = 0; m < 4; ++m) {
            #pragma unroll
            for (int r = 0; r < 4; ++r) {
                int grow = bm * 128 + wm * 64 + m * 16 + lc * 4 + r;
                out[(size_t)grow * N + col] = acc[m][n][r] + bv;
            }
        }
    }
}

extern "C" void kernel_launch(void* const* d_in, const int* in_sizes, int n_in,
                              void* d_out, int out_size, void* d_ws, size_t ws_size,
                              hipStream_t stream) {
    (void)in_sizes; (void)n_in; (void)out_size; (void)ws_size;
    const float* hs     = (const float*)d_in[0];
    const float* w_attn = (const float*)d_in[1];
    const float* b_attn = (const float*)d_in[2];
    const float* w_proj = (const float*)d_in[3];
    const float* b_proj = (const float*)d_in[4];
    float* out = (float*)d_out;
    char* ws = (char*)d_ws;

    short* Xb  = (short*)(ws + 0);         // 8 MiB  [4096][1024] bf16 (dead after qkv8)
    short* W1T = (short*)(ws + 8388608);   // 6 MiB  [3072][1024] bf16 (dead after qkv8)
    short* W2T = (short*)(ws + 14680064);  // 2 MiB  [1024][1024] bf16
    short* Qb  = (short*)(ws + 16777216);  // 8 MiB  [B][H][S][64] (pre-scaled 0.125*log2e)
    short* Kb  = (short*)(ws + 25165824);  // 8 MiB  [B][H][S][64]
    short* VTb = (short*)(ws + 33554432);  // 8 MiB  [B][H][64][S] (written by qkv8 directly)
    short* Ob  = (short*)(ws + 0);         // 8 MiB  [B][S][1024]  (over Xb, dead by attn)

    k_prep<<<dim3(8192), dim3(256), 0, stream>>>(hs, Xb, w_attn, W1T, w_proj, W2T);
    k_gemm_qkv8<<<dim3(256), dim3(512), 0, stream>>>(Xb, W1T, b_attn, Qb, Kb, VTb);
    k_attn<<<dim3(1024), dim3(256), 0, stream>>>(Qb, Kb, VTb, Ob);
    k_gemm_proj<<<dim3(8, 32), dim3(256), 0, stream>>>(Ob, W2T, b_proj, out);
}

// Round 15
// 97.595 us; speedup vs baseline: 2.0227x; 1.1308x over previous
//
#include <hip/hip_runtime.h>
#include <hip/hip_bf16.h>

typedef __attribute__((ext_vector_type(8))) short bf16x8;
typedef __attribute__((ext_vector_type(4))) float f32x4;
typedef __attribute__((ext_vector_type(4))) unsigned u32x4;

#define B_SZ 2
#define S_SZ 2048
#define D_SZ 1024
#define H_SZ 16
#define HD_SZ 64

static __device__ __forceinline__ short f2bf(float f) {
    unsigned u = __builtin_bit_cast(unsigned, f);
    u += 0x7FFFu + ((u >> 16) & 1u);
    return (short)(u >> 16);
}

static __device__ __forceinline__ float fexp2(float x) {
    float r; asm("v_exp_f32 %0, %1" : "=v"(r) : "v"(x)); return r;
}

static __device__ __forceinline__ unsigned cvtpk(float lo, float hi) {
    unsigned r; asm("v_cvt_pk_bf16_f32 %0, %1, %2" : "=v"(r) : "v"(lo), "v"(hi)); return r;
}

static __device__ __forceinline__ void gload16(const short* g, short* l) {
    __builtin_amdgcn_global_load_lds(
        (const __attribute__((address_space(1))) unsigned*)g,
        (__attribute__((address_space(3))) unsigned*)l,
        16, 0, 0);
}

#define SBAR() do { __builtin_amdgcn_sched_barrier(0); \
                    __builtin_amdgcn_s_barrier(); \
                    __builtin_amdgcn_sched_barrier(0); } while (0)

// ---------------- fused prep: fp32->bf16 cast + both weight transposes ----------------
__global__ __launch_bounds__(256) void k_prep(const float* __restrict__ hs, short* __restrict__ Xb,
                                              const float* __restrict__ w1, short* __restrict__ W1T,
                                              const float* __restrict__ w2, short* __restrict__ W2T) {
    __shared__ float tile[32][33];
    const int id = blockIdx.x;
    const int tid = threadIdx.x;
    if (id < 4096) {
        int i = (id * 256 + tid) * 4;
        float4 v = *reinterpret_cast<const float4*>(hs + i);
        short4 o;
        o.x = f2bf(v.x); o.y = f2bf(v.y); o.z = f2bf(v.z); o.w = f2bf(v.w);
        *reinterpret_cast<short4*>(Xb + i) = o;
        return;
    }
    const float* in;
    short* out;
    int N, bx, by;
    if (id < 7168) {
        int bid = id - 4096;
        in = w1; out = W1T; N = 3072;
        bx = bid % 96; by = bid / 96;
    } else {
        int bid = id - 7168;
        in = w2; out = W2T; N = 1024;
        bx = bid & 31; by = bid >> 5;
    }
    const int k0 = by * 32, n0 = bx * 32;
    const int tx = tid & 31, ty = tid >> 5;   // (32, 8)
    #pragma unroll
    for (int i = 0; i < 4; ++i)
        tile[ty + i * 8][tx] = in[(size_t)(k0 + ty + i * 8) * N + n0 + tx];
    __syncthreads();
    #pragma unroll
    for (int i = 0; i < 4; ++i)
        out[(size_t)(n0 + ty + i * 8) * 1024 + k0 + tx] = f2bf(tile[tx][ty + i * 8]);
}

// ---------------- QKV GEMM, 2-phase 256x192 (T3+T4+T2+T5), 256 blocks = full chip ----------------
__global__ __launch_bounds__(512, 1) void k_gemm_qkv8(
    const short* __restrict__ A, const short* __restrict__ Bt,
    const float* __restrict__ bias,
    short* __restrict__ Qo, short* __restrict__ Ko, short* __restrict__ VTo) {
    constexpr int K = 1024, NT = 16;
    __shared__ short As[2][256 * 64];   // 64 KB
    __shared__ short Bs[2][192 * 64];   // 48 KB
    const int tid = threadIdx.x;
    const int lane = tid & 63;
    const int w = tid >> 6;
    const int wr = w >> 2, wc = w & 3;
    const int lr = lane & 15, lc = lane >> 4;
    const int bid = blockIdx.x;
    const int xcd = bid & 7, local = bid >> 3;
    const int bm = (xcd >> 1) * 4 + (local >> 3);
    const int bn = (xcd & 1) * 8 + (local & 7);
    const size_t arow0 = (size_t)bm * 256;
    const size_t brow0 = (size_t)bn * 192;

    const int srl = tid >> 3;
    const int sc8 = (tid & 7) ^ (srl & 7);
    const int dcol = (tid & 7) * 8;

    f32x4 acc[8][3];
    #pragma unroll
    for (int m = 0; m < 8; ++m)
        #pragma unroll
        for (int n = 0; n < 3; ++n)
            acc[m][n] = (f32x4){0.f, 0.f, 0.f, 0.f};

    auto STAGE_A = [&](int T) {
        const int buf = T & 1;
        #pragma unroll
        for (int j = 0; j < 4; ++j) {
            int row = j * 64 + srl;
            gload16(&A[(arow0 + row) * K + T * 64 + sc8 * 8], &As[buf][row * 64 + dcol]);
        }
    };
    auto STAGE_B = [&](int T) {
        const int buf = T & 1;
        #pragma unroll
        for (int j = 0; j < 3; ++j) {
            int row = j * 64 + srl;
            gload16(&Bt[(brow0 + row) * K + T * 64 + sc8 * 8], &Bs[buf][row * 64 + dcol]);
        }
    };

    const int rx = (lr & 7) * 8;
    auto LDA = [&](int buf, int rowoff, int c) {
        return *reinterpret_cast<const bf16x8*>(
            &As[buf][(wr * 128 + rowoff + lr) * 64 + (((c * 32) + lc * 8) ^ rx)]);
    };
    auto LDB = [&](int buf, int n, int c) {
        return *reinterpret_cast<const bf16x8*>(
            &Bs[buf][(wc * 48 + n * 16 + lr) * 64 + (((c * 32) + lc * 8) ^ rx)]);
    };

    bf16x8 at[4][2];
    bf16x8 bfr[3][2];

    STAGE_A(0); STAGE_B(0); STAGE_B(1);
    asm volatile("s_waitcnt vmcnt(3)" ::: "memory");
    SBAR();

    for (int T = 0; T < NT; ++T) {
        const int buf = T & 1;
        // ---- phase 1: read A-mh0 + B all; stage A(T+1); MFMA mh0 x n
        #pragma unroll
        for (int m = 0; m < 4; ++m)
            #pragma unroll
            for (int c = 0; c < 2; ++c)
                at[m][c] = LDA(buf, m * 16, c);
        #pragma unroll
        for (int n = 0; n < 3; ++n)
            #pragma unroll
            for (int c = 0; c < 2; ++c)
                bfr[n][c] = LDB(buf, n, c);
        if (T + 1 < NT) STAGE_A(T + 1);
        SBAR();
        __builtin_amdgcn_s_setprio(1);
        #pragma unroll
        for (int m = 0; m < 4; ++m)
            #pragma unroll
            for (int n = 0; n < 3; ++n)
                #pragma unroll
                for (int c = 0; c < 2; ++c)
                    acc[m][n] = __builtin_amdgcn_mfma_f32_16x16x32_bf16(at[m][c], bfr[n][c], acc[m][n], 0, 0, 0);
        __builtin_amdgcn_s_setprio(0);
        SBAR();
        // ---- phase 2: read A-mh1; stage B(T+2); counted vmcnt(3); MFMA mh1 x n
        #pragma unroll
        for (int m = 0; m < 4; ++m)
            #pragma unroll
            for (int c = 0; c < 2; ++c)
                at[m][c] = LDA(buf, 64 + m * 16, c);
        if (T + 2 < NT) {
            STAGE_B(T + 2);
            asm volatile("s_waitcnt vmcnt(3)" ::: "memory");
        } else {
            asm volatile("s_waitcnt vmcnt(0)" ::: "memory");
        }
        SBAR();
        __builtin_amdgcn_s_setprio(1);
        #pragma unroll
        for (int m = 0; m < 4; ++m)
            #pragma unroll
            for (int n = 0; n < 3; ++n)
                #pragma unroll
                for (int c = 0; c < 2; ++c)
                    acc[4 + m][n] = __builtin_amdgcn_mfma_f32_16x16x32_bf16(at[m][c], bfr[n][c], acc[4 + m][n], 0, 0, 0);
        __builtin_amdgcn_s_setprio(0);
        SBAR();
    }

    #pragma unroll
    for (int n = 0; n < 3; ++n) {
        const int col = bn * 192 + wc * 48 + n * 16 + lr;
        const float bv = bias[col];
        if (col < 2048) {
            const bool isq = (col < 1024);
            const float scale = isq ? 0.18033688011112042f : 1.0f;   // 0.125 * log2(e)
            short* dst = isq ? Qo : Ko;
            const int dg = col & 1023;
            const int hh = dg >> 6, dd = dg & 63;
            #pragma unroll
            for (int m = 0; m < 8; ++m) {
                #pragma unroll
                for (int r = 0; r < 4; ++r) {
                    int grow = bm * 256 + wr * 128 + m * 16 + lc * 4 + r;
                    int b = grow >> 11, s = grow & 2047;
                    dst[(((size_t)(b * H_SZ + hh)) * S_SZ + s) * HD_SZ + dd] = f2bf((acc[m][n][r] + bv) * scale);
                }
            }
        } else {
            const int dv = col - 2048;
            const int hh = dv >> 6, dt = dv & 63;
            #pragma unroll
            for (int m = 0; m < 8; ++m) {
                int grow = bm * 256 + wr * 128 + m * 16 + lc * 4;
                int b = grow >> 11, s = grow & 2047;
                short4 st;
                st.x = f2bf(acc[m][n][0] + bv);
                st.y = f2bf(acc[m][n][1] + bv);
                st.z = f2bf(acc[m][n][2] + bv);
                st.w = f2bf(acc[m][n][3] + bv);
                *reinterpret_cast<short4*>(
                    &VTo[(((size_t)(b * H_SZ + hh)) * HD_SZ + dt) * S_SZ + s]) = st;
            }
        }
    }
}

// ---------------- flash attention: R12 structure + 3-buffer counted-vmcnt staging (T4) ----------------
// 1024 single-qtile blocks, swapped QK^T, exp2 softmax, cvt_pk, T12 exchange, balanced qt.
// Tile kt's loads issued at kt-2, waited with vmcnt(4) at end of kt-1 -> 2 iterations in flight.
__global__ __launch_bounds__(256) void k_attn(const short* __restrict__ Q,
                                              const short* __restrict__ Kv,
                                              const short* __restrict__ VT,
                                              short* __restrict__ O) {
    __shared__ short Ks[3][64 * 64];
    __shared__ short Vs[3][64 * 64];
    const int id = blockIdx.x;
    const int bh = ((id & 7) << 2) | ((id >> 3) & 3);
    const int h = bh & 15;
    const int bb = bh >> 4;
    const int g = id >> 5, oct = g >> 3, gr = g & 7;
    const int qt = (oct == 0) ? 31 - gr : (oct == 1) ? 16 + gr : (oct == 2) ? 15 - gr : gr;
    const int tid = threadIdx.x;
    const int lane = tid & 63, w = tid >> 6;        // w 0..3
    const int lr = lane & 15, lc = lane >> 4;
    const int qrow0 = qt * 64 + w * 16;
    const size_t base = (size_t)bh * S_SZ * HD_SZ;

    bf16x8 qf[2];
    #pragma unroll
    for (int c = 0; c < 2; ++c)
        qf[c] = *reinterpret_cast<const bf16x8*>(&Q[base + (size_t)(qrow0 + lr) * HD_SZ + c * 32 + lc * 8]);

    float l_run = 0.f;
    f32x4 o_acc[4];
    #pragma unroll
    for (int n = 0; n < 4; ++n) o_acc[n] = (f32x4){0.f, 0.f, 0.f, 0.f};

    const int srow = tid >> 3;
    const int sslot = (tid & 7) ^ (srow & 7);
    const short* kp = &Kv[base + (size_t)srow * HD_SZ + sslot * 8];
    const short* vp = &VT[base + (size_t)srow * S_SZ + sslot * 8];
    auto STAGE = [&](int b) {
        gload16(kp, &Ks[b][tid * 8]);
        gload16(kp + 2048, &Ks[b][2048 + tid * 8]);
        gload16(vp, &Vs[b][tid * 8]);
        gload16(vp + 32 * S_SZ, &Vs[b][2048 + tid * 8]);
        kp += 4096; vp += 64;
    };

    const int q_row = qrow0 + lr;
    const int rxa = (lr & 7) * 8;
    const bool b0 = (lane & 16) != 0;
    const bool b1 = (lane & 32) != 0;

    // prologue: tiles 0,1 into bufs 0,1; tile0 must land, tile1 may fly
    STAGE(0);
    if (qt >= 1) {
        STAGE(1);
        asm volatile("s_waitcnt vmcnt(4)" ::: "memory");
    } else {
        asm volatile("s_waitcnt vmcnt(0)" ::: "memory");
    }
    SBAR();

    int bufc = 0, stc = 2;   // kt%3, (kt+2)%3
    for (int kt = 0; kt <= qt; ++kt) {
        if (kt + 2 <= qt) STAGE(stc);
        {
            f32x4 sf[4];
            #pragma unroll
            for (int n = 0; n < 4; ++n) {
                f32x4 z = (f32x4){0.f, 0.f, 0.f, 0.f};
                #pragma unroll
                for (int c = 0; c < 2; ++c) {
                    bf16x8 kf = *reinterpret_cast<const bf16x8*>(
                        &Ks[bufc][(n * 16 + lr) * 64 + ((c * 32 + lc * 8) ^ rxa)]);
                    z = __builtin_amdgcn_mfma_f32_16x16x32_bf16(kf, qf[c], z, 0, 0, 0);
                }
                sf[n] = z;
            }
            if (kt == qt) {
                const int kb = kt * 64 + lc * 4 - q_row;
                #pragma unroll
                for (int n = 0; n < 4; ++n)
                    #pragma unroll
                    for (int r = 0; r < 4; ++r)
                        sf[n][r] = (kb + n * 16 + r > 0) ? -14427.0f : sf[n][r];
            }
            float rs = 0.f;
            #pragma unroll
            for (int n = 0; n < 4; ++n)
                #pragma unroll
                for (int r = 0; r < 4; ++r) {
                    float pv = fexp2(sf[n][r]);
                    sf[n][r] = pv;
                    rs += pv;
                }
            l_run += rs;
            unsigned Apk0 = cvtpk(sf[0][0], sf[0][1]), Apk1 = cvtpk(sf[0][2], sf[0][3]);
            unsigned Bpk0 = cvtpk(sf[1][0], sf[1][1]), Bpk1 = cvtpk(sf[1][2], sf[1][3]);
            unsigned Cpk0 = cvtpk(sf[2][0], sf[2][1]), Cpk1 = cvtpk(sf[2][2], sf[2][3]);
            unsigned Dpk0 = cvtpk(sf[3][0], sf[3][1]), Dpk1 = cvtpk(sf[3][2], sf[3][3]);
            unsigned x0 = __shfl_xor(b0 ? Apk0 : Bpk0, 16);
            unsigned x1 = __shfl_xor(b0 ? Apk1 : Bpk1, 16);
            unsigned x2 = __shfl_xor(b0 ? Cpk0 : Dpk0, 16);
            unsigned x3 = __shfl_xor(b0 ? Cpk1 : Dpk1, 16);
            unsigned y0 = __shfl_xor(b1 ? Apk0 : Bpk0, 32);
            unsigned y1 = __shfl_xor(b1 ? Apk1 : Bpk1, 32);
            unsigned y2 = __shfl_xor(b1 ? Cpk0 : Dpk0, 32);
            unsigned y3 = __shfl_xor(b1 ? Cpk1 : Dpk1, 32);
            unsigned z0 = __shfl_xor(b1 ? Apk0 : Bpk0, 48);
            unsigned z1 = __shfl_xor(b1 ? Apk1 : Bpk1, 48);
            unsigned z2 = __shfl_xor(b1 ? Cpk0 : Dpk0, 48);
            unsigned z3 = __shfl_xor(b1 ? Cpk1 : Dpk1, 48);
            u32x4 pv0 = { b1 ? (b0 ? x0 : y0) : (b0 ? z0 : Apk0),
                          b1 ? (b0 ? x1 : y1) : (b0 ? z1 : Apk1),
                          b1 ? (b0 ? Bpk0 : z0) : (b0 ? y0 : x0),
                          b1 ? (b0 ? Bpk1 : z1) : (b0 ? y1 : x1) };
            u32x4 pv1 = { b1 ? (b0 ? x2 : y2) : (b0 ? z2 : Cpk0),
                          b1 ? (b0 ? x3 : y3) : (b0 ? z3 : Cpk1),
                          b1 ? (b0 ? Dpk0 : z2) : (b0 ? y2 : x2),
                          b1 ? (b0 ? Dpk1 : z3) : (b0 ? y3 : x3) };
            bf16x8 paA = __builtin_bit_cast(bf16x8, pv0);
            bf16x8 paB = __builtin_bit_cast(bf16x8, pv1);
            #pragma unroll
            for (int c = 0; c < 2; ++c) {
                bf16x8 pa = c ? paB : paA;
                #pragma unroll
                for (int n = 0; n < 4; ++n) {
                    bf16x8 vf = *reinterpret_cast<const bf16x8*>(
                        &Vs[bufc][(n * 16 + lr) * 64 + ((c * 32 + lc * 8) ^ rxa)]);
                    o_acc[n] = __builtin_amdgcn_mfma_f32_16x16x32_bf16(pa, vf, o_acc[n], 0, 0, 0);
                }
            }
        }
        if (kt < qt) {
            if (kt + 2 <= qt) asm volatile("s_waitcnt vmcnt(4)" ::: "memory");
            else              asm volatile("s_waitcnt vmcnt(0)" ::: "memory");
            SBAR();
        }
        bufc = (bufc == 2) ? 0 : bufc + 1;
        stc  = (stc == 2) ? 0 : stc + 1;
    }

    l_run += __shfl_xor(l_run, 16);
    l_run += __shfl_xor(l_run, 32);
    float li[4];
    #pragma unroll
    for (int r = 0; r < 4; ++r)
        li[r] = 1.0f / __shfl(l_run, lc * 4 + r);
    #pragma unroll
    for (int n = 0; n < 4; ++n) {
        #pragma unroll
        for (int r = 0; r < 4; ++r) {
            float v = o_acc[n][r] * li[r];
            int s = qrow0 + lc * 4 + r;
            O[((size_t)bb * S_SZ + s) * D_SZ + h * 64 + n * 16 + lr] = f2bf(v);
        }
    }
}

// ---------------- proj GEMM, 2-phase 128x128 counted-vmcnt (qkv8 structure), 256 blocks ----------------
// 4 waves (wr,wc in {0,1}), acc[4][4]; B-frags held across phases so B(T+2) stages into live buf.
__global__ __launch_bounds__(256, 2) void k_gemm_proj(
    const short* __restrict__ A, const short* __restrict__ Bt,
    const float* __restrict__ bias, float* __restrict__ out) {
    constexpr int K = 1024, NT = 16, N = 1024;
    __shared__ short As[2][128 * 64];   // 32 KB
    __shared__ short Bs[2][128 * 64];   // 32 KB
    const int tid = threadIdx.x;
    const int lane = tid & 63;
    const int w = tid >> 6;
    const int wr = w >> 1, wc = w & 1;
    const int lr = lane & 15, lc = lane >> 4;
    const int bid = blockIdx.x;
    const int xcd = bid & 7, local = bid >> 3;      // 0..31
    const int bm = xcd * 4 + (local & 3);           // 0..31
    const int bn = local >> 2;                      // 0..7
    const size_t arow0 = (size_t)bm * 128;
    const size_t brow0 = (size_t)bn * 128;

    const int srl = tid >> 3;                       // 0..31
    const int sc8 = (tid & 7) ^ (srl & 7);
    const int dcol = (tid & 7) * 8;

    f32x4 acc[4][4];
    #pragma unroll
    for (int m = 0; m < 4; ++m)
        #pragma unroll
        for (int n = 0; n < 4; ++n)
            acc[m][n] = (f32x4){0.f, 0.f, 0.f, 0.f};

    auto STAGE_A = [&](int T) {
        const int buf = T & 1;
        #pragma unroll
        for (int j = 0; j < 4; ++j) {
            int row = j * 32 + srl;
            gload16(&A[(arow0 + row) * K + T * 64 + sc8 * 8], &As[buf][row * 64 + dcol]);
        }
    };
    auto STAGE_B = [&](int T) {
        const int buf = T & 1;
        #pragma unroll
        for (int j = 0; j < 4; ++j) {
            int row = j * 32 + srl;
            gload16(&Bt[(brow0 + row) * K + T * 64 + sc8 * 8], &Bs[buf][row * 64 + dcol]);
        }
    };

    const int rx = (lr & 7) * 8;
    auto LDA = [&](int buf, int rowoff, int c) {
        return *reinterpret_cast<const bf16x8*>(
            &As[buf][(wr * 64 + rowoff + lr) * 64 + (((c * 32) + lc * 8) ^ rx)]);
    };
    auto LDB = [&](int buf, int n, int c) {
        return *reinterpret_cast<const bf16x8*>(
            &Bs[buf][(wc * 64 + n * 16 + lr) * 64 + (((c * 32) + lc * 8) ^ rx)]);
    };

    bf16x8 at[2][2];
    bf16x8 bfr[4][2];

    STAGE_A(0); STAGE_B(0); STAGE_B(1);
    asm volatile("s_waitcnt vmcnt(4)" ::: "memory");
    SBAR();

    for (int T = 0; T < NT; ++T) {
        const int buf = T & 1;
        // ---- phase 1: read B all + A mh0; stage A(T+1); MFMA mh0
        #pragma unroll
        for (int m = 0; m < 2; ++m)
            #pragma unroll
            for (int c = 0; c < 2; ++c)
                at[m][c] = LDA(buf, m * 16, c);
        #pragma unroll
        for (int n = 0; n < 4; ++n)
            #pragma unroll
            for (int c = 0; c < 2; ++c)
                bfr[n][c] = LDB(buf, n, c);
        if (T + 1 < NT) STAGE_A(T + 1);
        SBAR();
        __builtin_amdgcn_s_setprio(1);
        #pragma unroll
        for (int m = 0; m < 2; ++m)
            #pragma unroll
            for (int n = 0; n < 4; ++n)
                #pragma unroll
                for (int c = 0; c < 2; ++c)
                    acc[m][n] = __builtin_amdgcn_mfma_f32_16x16x32_bf16(at[m][c], bfr[n][c], acc[m][n], 0, 0, 0);
        __builtin_amdgcn_s_setprio(0);
        SBAR();
        // ---- phase 2: read A mh1; stage B(T+2) (same buf, B reads done); counted vmcnt
        #pragma unroll
        for (int m = 0; m < 2; ++m)
            #pragma unroll
            for (int c = 0; c < 2; ++c)
                at[m][c] = LDA(buf, 32 + m * 16, c);
        if (T + 2 < NT) {
            STAGE_B(T + 2);
            asm volatile("s_waitcnt vmcnt(4)" ::: "memory");
        } else {
            asm volatile("s_waitcnt vmcnt(0)" ::: "memory");
        }
        SBAR();
        __builtin_amdgcn_s_setprio(1);
        #pragma unroll
        for (int m = 0; m < 2; ++m)
            #pragma unroll
            for (int n = 0; n < 4; ++n)
                #pragma unroll
                for (int c = 0; c < 2; ++c)
                    acc[2 + m][n] = __builtin_amdgcn_mfma_f32_16x16x32_bf16(at[m][c], bfr[n][c], acc[2 + m][n], 0, 0, 0);
        __builtin_amdgcn_s_setprio(0);
        SBAR();
    }

    #pragma unroll
    for (int n = 0; n < 4; ++n) {
        const int col = bn * 128 + wc * 64 + n * 16 + lr;
        const float bv = bias[col];
        #pragma unroll
        for (int m = 0; m < 4; ++m) {
            #pragma unroll
            for (int r = 0; r < 4; ++r) {
                int grow = bm * 128 + wr * 64 + m * 16 + lc * 4 + r;
                out[(size_t)grow * N + col] = acc[m][n][r] + bv;
            }
        }
    }
}

extern "C" void kernel_launch(void* const* d_in, const int* in_sizes, int n_in,
                              void* d_out, int out_size, void* d_ws, size_t ws_size,
                              hipStream_t stream) {
    (void)in_sizes; (void)n_in; (void)out_size; (void)ws_size;
    const float* hs     = (const float*)d_in[0];
    const float* w_attn = (const float*)d_in[1];
    const float* b_attn = (const float*)d_in[2];
    const float* w_proj = (const float*)d_in[3];
    const float* b_proj = (const float*)d_in[4];
    float* out = (float*)d_out;
    char* ws = (char*)d_ws;

    short* Xb  = (short*)(ws + 0);         // 8 MiB  (dead after qkv8)
    short* W1T = (short*)(ws + 8388608);   // 6 MiB  (dead after qkv8)
    short* W2T = (short*)(ws + 14680064);  // 2 MiB
    short* Qb  = (short*)(ws + 16777216);  // 8 MiB  (pre-scaled 0.125*log2e)
    short* Kb  = (short*)(ws + 25165824);  // 8 MiB
    short* VTb = (short*)(ws + 33554432);  // 8 MiB  [B][H][64][S]
    short* Ob  = (short*)(ws + 0);         // 8 MiB  [B][S][1024] (over Xb)

    k_prep<<<dim3(8192), dim3(256), 0, stream>>>(hs, Xb, w_attn, W1T, w_proj, W2T);
    k_gemm_qkv8<<<dim3(256), dim3(512), 0, stream>>>(Xb, W1T, b_attn, Qb, Kb, VTb);
    k_attn<<<dim3(1024), dim3(256), 0, stream>>>(Qb, Kb, VTb, Ob);
    k_gemm_proj<<<dim3(256), dim3(256), 0, stream>>>(Ob, W2T, b_proj, out);
}